// Round 1
// baseline (2999.947 us; speedup 1.0000x reference)
//
#include <hip/hip_runtime.h>
#include <stdint.h>

#define NE   8      // experts
#define TOPK 2
#define DD   2048   // hidden
#define MMM  7168   // mlp
#define NT   4096   // tokens (B*S)
#define TRR  (NT*TOPK)

typedef __attribute__((ext_vector_type(8))) short short8;
typedef __attribute__((ext_vector_type(4))) short short4v;
typedef __attribute__((ext_vector_type(4))) float f32x4;

__device__ __forceinline__ unsigned short f2bf(float f) {
    union { float f; uint32_t u; } v; v.f = f;
    uint32_t u = v.u;
    return (unsigned short)((u + 0x7FFFu + ((u >> 16) & 1u)) >> 16);  // RNE
}

// ---------------- router: one wave per token ----------------
__global__ __launch_bounds__(256) void router_k(const float* __restrict__ x,
                                                const float* __restrict__ gw,
                                                int* __restrict__ topk_idx,
                                                float* __restrict__ topk_w,
                                                int* __restrict__ counts) {
    int wv = threadIdx.x >> 6, lane = threadIdx.x & 63;
    int t = blockIdx.x * 4 + wv;
    const float* xr = x + (size_t)t * DD;
    float acc[NE];
#pragma unroll
    for (int e = 0; e < NE; ++e) acc[e] = 0.f;
    for (int d = lane; d < DD; d += 64) {
        float xv = xr[d];
        const float* g = gw + (size_t)d * NE;
#pragma unroll
        for (int e = 0; e < NE; ++e) acc[e] += xv * g[e];
    }
#pragma unroll
    for (int e = 0; e < NE; ++e) {
#pragma unroll
        for (int off = 32; off > 0; off >>= 1) acc[e] += __shfl_xor(acc[e], off);
    }
    // top-2 (ties -> lowest index, matches lax.top_k)
    int b0 = 0; float v0 = acc[0];
#pragma unroll
    for (int e = 1; e < NE; ++e) if (acc[e] > v0) { v0 = acc[e]; b0 = e; }
    int b1 = -1; float v1 = -1e30f;
#pragma unroll
    for (int e = 0; e < NE; ++e) if (e != b0 && acc[e] > v1) { v1 = acc[e]; b1 = e; }
    float w0 = 1.f / (1.f + expf(v1 - v0));   // softmax-top2 renormalized
    if (lane == 0) {
        topk_idx[t * 2] = b0; topk_idx[t * 2 + 1] = b1;
        topk_w[t * 2] = w0;   topk_w[t * 2 + 1] = 1.f - w0;
        atomicAdd(&counts[b0], 1);
        atomicAdd(&counts[b1], 1);
    }
}

// ---------------- scan: offsets + tile table ----------------
__global__ void scan_k(const int* __restrict__ counts, int* __restrict__ offsets,
                       int* __restrict__ tileOff) {
    if (threadIdx.x == 0) {
        int o = 0, to = 0;
        for (int e = 0; e < NE; ++e) {
            offsets[e] = o; tileOff[e] = to;
            o += counts[e]; to += (counts[e] + 127) >> 7;
        }
        offsets[NE] = o; tileOff[NE] = to;
    }
}

// ---------------- scatter: assign sorted row slots ----------------
__global__ void scatter_k(const int* __restrict__ topk_idx, const float* __restrict__ topk_w,
                          const int* __restrict__ offsets, int* __restrict__ cursors,
                          int* __restrict__ row_token, float* __restrict__ row_w) {
    int i = blockIdx.x * blockDim.x + threadIdx.x;
    if (i >= TRR) return;
    int e = topk_idx[i];
    int pos = offsets[e] + atomicAdd(&cursors[e], 1);
    row_token[pos] = i >> 1;
    row_w[pos] = topk_w[i];
}

// ---------------- gather: x rows -> bf16 xs (grouped order) ----------------
__global__ __launch_bounds__(256) void gather_k(const float* __restrict__ x,
                                                const int* __restrict__ row_token,
                                                unsigned short* __restrict__ xs) {
    int i = blockIdx.x * blockDim.x + threadIdx.x;   // one thread per 8 elems
    int row = i >> 8;                 // DD/8 = 256 chunks per row
    int off = (i & 255) * 8;
    int tok = row_token[row];
    const float4* sp = (const float4*)(x + (size_t)tok * DD + off);
    float4 a = sp[0], b = sp[1];
    short8 h;
    h[0] = (short)f2bf(a.x); h[1] = (short)f2bf(a.y);
    h[2] = (short)f2bf(a.z); h[3] = (short)f2bf(a.w);
    h[4] = (short)f2bf(b.x); h[5] = (short)f2bf(b.y);
    h[6] = (short)f2bf(b.z); h[7] = (short)f2bf(b.w);
    *(short8*)(xs + (size_t)row * DD + off) = h;
}

// ---------------- GEMM1: h = silu(xs@w1) * (xs@w3), bf16 out ----------------
// grid: (72 row-tile slots, 56 n-tiles of 128 over M)
__global__ __launch_bounds__(256, 2) void gemm1_k(const unsigned short* __restrict__ xs,
                                                  const float* __restrict__ w1,
                                                  const float* __restrict__ w3,
                                                  unsigned short* __restrict__ H,
                                                  const int* __restrict__ counts,
                                                  const int* __restrict__ offsets,
                                                  const int* __restrict__ tileOff) {
    int bx = blockIdx.x;
    if (bx >= tileOff[NE]) return;
    int e = 0;
#pragma unroll
    for (int i = 0; i < NE; ++i) if (bx >= tileOff[i] && bx < tileOff[i + 1]) e = i;
    int tloc = bx - tileOff[e];
    int r0 = offsets[e] + tloc * 128;
    int cnt = counts[e];
    int n0 = blockIdx.y * 128;
    int tid = threadIdx.x;

    __shared__ unsigned short sA[128 * 32];   // [row][k]
    __shared__ unsigned short sB1[128 * 32];  // [k4][n][k8]
    __shared__ unsigned short sB3[128 * 32];

    f32x4 acc1[4][4] = {};
    f32x4 acc3[4][4] = {};

    int w = tid >> 6, lane = tid & 63;
    int wr = (w >> 1) * 64, wc = (w & 1) * 64;
    int quad = lane >> 4, ln = lane & 15;

    const float* wB = (tid < 128 ? w1 : w3) + (size_t)e * DD * MMM;
    unsigned short* sB = (tid < 128) ? sB1 : sB3;
    int j  = tid & 127;
    int mq = (j & 31) * 4;       // n offset within tile
    int d8 = (j >> 5) * 8;       // k offset {0,8,16,24}

    for (int kk = 0; kk < DD; kk += 32) {
        // stage A (bf16, k-contiguous): 512 chunks of 8 halves
#pragma unroll
        for (int it = 0; it < 2; ++it) {
            int chunk = it * 256 + tid;
            int row = chunk >> 2, k8 = (chunk & 3) * 8;
            short8 v = *(const short8*)(xs + (size_t)(r0 + row) * DD + kk + k8);
            *(short8*)&sA[row * 32 + k8] = v;
        }
        // stage B: f32 -> bf16 transpose into [k4][n][k8]
        {
            const float* wp = wB + (size_t)(kk + d8) * MMM + (n0 + mq);
            float vv[8][4];
#pragma unroll
            for (int r = 0; r < 8; ++r) {
                float4 t4 = *(const float4*)(wp + (size_t)r * MMM);
                vv[r][0] = t4.x; vv[r][1] = t4.y; vv[r][2] = t4.z; vv[r][3] = t4.w;
            }
#pragma unroll
            for (int c = 0; c < 4; ++c) {
                short8 hs;
#pragma unroll
                for (int r = 0; r < 8; ++r) hs[r] = (short)f2bf(vv[r][c]);
                *(short8*)&sB[(((d8 >> 3) * 128) + mq + c) * 8] = hs;
            }
        }
        __syncthreads();
        // compute
        short8 af[4];
#pragma unroll
        for (int mi = 0; mi < 4; ++mi)
            af[mi] = *(const short8*)&sA[(wr + mi * 16 + ln) * 32 + quad * 8];
#pragma unroll
        for (int ni = 0; ni < 4; ++ni) {
            short8 bf1 = *(const short8*)&sB1[(quad * 128 + wc + ni * 16 + ln) * 8];
            short8 bf3 = *(const short8*)&sB3[(quad * 128 + wc + ni * 16 + ln) * 8];
#pragma unroll
            for (int mi = 0; mi < 4; ++mi) {
                acc1[mi][ni] = __builtin_amdgcn_mfma_f32_16x16x32_bf16(af[mi], bf1, acc1[mi][ni], 0, 0, 0);
                acc3[mi][ni] = __builtin_amdgcn_mfma_f32_16x16x32_bf16(af[mi], bf3, acc3[mi][ni], 0, 0, 0);
            }
        }
        __syncthreads();
    }
    // epilogue: silu(a1)*a3 -> bf16 H
#pragma unroll
    for (int mi = 0; mi < 4; ++mi) {
#pragma unroll
        for (int r = 0; r < 4; ++r) {
            int row = wr + mi * 16 + quad * 4 + r;
            int lrow = tloc * 128 + row;
            if (lrow < cnt) {
                size_t base = (size_t)(r0 + row) * MMM + n0 + wc;
#pragma unroll
                for (int ni = 0; ni < 4; ++ni) {
                    float x1 = acc1[mi][ni][r];
                    float x3 = acc3[mi][ni][r];
                    float hv = (x1 / (1.f + __expf(-x1))) * x3;
                    H[base + ni * 16 + ln] = f2bf(hv);
                }
            }
        }
    }
}

// ---------------- GEMM2: out += row_w * (H @ w2) ----------------
// grid: (72 row-tile slots, 16 n-tiles of 128 over D)
__global__ __launch_bounds__(256, 2) void gemm2_k(const unsigned short* __restrict__ H,
                                                  const float* __restrict__ w2,
                                                  float* __restrict__ out,
                                                  const int* __restrict__ counts,
                                                  const int* __restrict__ offsets,
                                                  const int* __restrict__ tileOff,
                                                  const int* __restrict__ row_token,
                                                  const float* __restrict__ row_w) {
    int bx = blockIdx.x;
    if (bx >= tileOff[NE]) return;
    int e = 0;
#pragma unroll
    for (int i = 0; i < NE; ++i) if (bx >= tileOff[i] && bx < tileOff[i + 1]) e = i;
    int tloc = bx - tileOff[e];
    int r0 = offsets[e] + tloc * 128;
    int cnt = counts[e];
    int n0 = blockIdx.y * 128;
    int tid = threadIdx.x;

    __shared__ unsigned short sA[128 * 32];
    __shared__ unsigned short sB[128 * 32];   // [k4][n][k8]

    f32x4 acc[4][4] = {};

    int w = tid >> 6, lane = tid & 63;
    int wr = (w >> 1) * 64, wc = (w & 1) * 64;
    int quad = lane >> 4, ln = lane & 15;

    int mq = (tid & 31) * 4;       // n offset
    int d4 = (tid >> 5) * 4;       // k offset {0,4,...,28}
    const float* wBase = w2 + (size_t)e * MMM * DD;

    for (int kk = 0; kk < MMM; kk += 32) {
#pragma unroll
        for (int it = 0; it < 2; ++it) {
            int chunk = it * 256 + tid;
            int row = chunk >> 2, k8 = (chunk & 3) * 8;
            short8 v = *(const short8*)(H + (size_t)(r0 + row) * MMM + kk + k8);
            *(short8*)&sA[row * 32 + k8] = v;
        }
        {
            const float* wp = wBase + (size_t)(kk + d4) * DD + (n0 + mq);
            float vv[4][4];
#pragma unroll
            for (int r = 0; r < 4; ++r) {
                float4 t4 = *(const float4*)(wp + (size_t)r * DD);
                vv[r][0] = t4.x; vv[r][1] = t4.y; vv[r][2] = t4.z; vv[r][3] = t4.w;
            }
#pragma unroll
            for (int c = 0; c < 4; ++c) {
                short4v hs;
#pragma unroll
                for (int r = 0; r < 4; ++r) hs[r] = (short)f2bf(vv[r][c]);
                *(short4v*)&sB[((d4 >> 3) * 128 + mq + c) * 8 + (d4 & 7)] = hs;
            }
        }
        __syncthreads();
        short8 af[4];
#pragma unroll
        for (int mi = 0; mi < 4; ++mi)
            af[mi] = *(const short8*)&sA[(wr + mi * 16 + ln) * 32 + quad * 8];
#pragma unroll
        for (int ni = 0; ni < 4; ++ni) {
            short8 bfr = *(const short8*)&sB[(quad * 128 + wc + ni * 16 + ln) * 8];
#pragma unroll
            for (int mi = 0; mi < 4; ++mi)
                acc[mi][ni] = __builtin_amdgcn_mfma_f32_16x16x32_bf16(af[mi], bfr, acc[mi][ni], 0, 0, 0);
        }
        __syncthreads();
    }
#pragma unroll
    for (int mi = 0; mi < 4; ++mi) {
#pragma unroll
        for (int r = 0; r < 4; ++r) {
            int row = wr + mi * 16 + quad * 4 + r;
            int lrow = tloc * 128 + row;
            if (lrow < cnt) {
                int tok = row_token[r0 + row];
                float wt = row_w[r0 + row];
                float* op = out + (size_t)tok * DD + n0 + wc;
#pragma unroll
                for (int ni = 0; ni < 4; ++ni)
                    atomicAdd(&op[ni * 16 + ln], wt * acc[mi][ni][r]);
            }
        }
    }
}

// ---------------- launcher ----------------
extern "C" void kernel_launch(void* const* d_in, const int* in_sizes, int n_in,
                              void* d_out, int out_size, void* d_ws, size_t ws_size,
                              hipStream_t stream) {
    const float* x  = (const float*)d_in[0];
    const float* gw = (const float*)d_in[1];
    const float* w1 = (const float*)d_in[2];
    const float* w2 = (const float*)d_in[3];
    const float* w3 = (const float*)d_in[4];
    float* out = (float*)d_out;
    char* ws = (char*)d_ws;

    // ws layout
    int*   counts    = (int*)(ws + 0);        // 8
    int*   cursors   = (int*)(ws + 32);       // 8
    int*   offsets   = (int*)(ws + 64);       // 9
    int*   tileOff   = (int*)(ws + 128);      // 9
    int*   topk_idx  = (int*)(ws + 256);      // TRR
    float* topk_w    = (float*)(ws + 33024);  // TRR
    int*   row_token = (int*)(ws + 65792);    // TRR
    float* row_w     = (float*)(ws + 98560);  // TRR
    unsigned short* xs   = (unsigned short*)(ws + 131328);    // (TRR+128)*DD bf16
    unsigned short* Hbuf = (unsigned short*)(ws + 131328 + (size_t)(TRR + 128) * DD * 2);

    hipMemsetAsync(ws, 0, 256, stream);                         // counters/offsets
    hipMemsetAsync(out, 0, (size_t)NT * DD * sizeof(float), stream);

    router_k<<<NT / 4, 256, 0, stream>>>(x, gw, topk_idx, topk_w, counts);
    scan_k<<<1, 64, 0, stream>>>(counts, offsets, tileOff);
    scatter_k<<<TRR / 256, 256, 0, stream>>>(topk_idx, topk_w, offsets, cursors, row_token, row_w);
    gather_k<<<(TRR * (DD / 8)) / 256, 256, 0, stream>>>(x, row_token, xs);
    gemm1_k<<<dim3(72, MMM / 128), 256, 0, stream>>>(xs, w1, w3, Hbuf, counts, offsets, tileOff);
    gemm2_k<<<dim3(72, DD / 128), 256, 0, stream>>>(Hbuf, w2, out, counts, offsets, tileOff, row_token, row_w);
}